// Round 4
// baseline (210.939 us; speedup 1.0000x reference)
//
#include <hip/hip_runtime.h>
#include <hip/hip_bf16.h>

// Problem constants (fixed by the reference): N_CLASS=200, N_MU=1024, D=512, K=512
constexpr int N_CLASS = 200;
constexpr int N_MU    = 1024;
constexpr int DIM     = 512;
constexpr int KIN     = 512;
constexpr int NCAND   = N_MU + KIN;      // 1536 candidates
constexpr int SORTN   = 2048;            // next pow2
constexpr int RPB     = 8;               // rows per output block

// clang ext-vector (NOT HIP_vector_type) so __builtin_nontemporal_* accepts it
typedef float f4 __attribute__((ext_vector_type(4)));

// ---------------------------------------------------------------------------
// Kernel 1: per-class stable top-1024 selection via bitonic sort.
// Key = (~sortable(score) << 32) | index  -> ascending sort == descending
// score with lower-index-first tie break (matches XLA top_k stability).
// Workspace indexed by CLASS id c. Sets flags[c]=1.
// ---------------------------------------------------------------------------
__global__ __launch_bounds__(1024) void sort_kernel(
    const float* __restrict__ q_sc,    // [N_CLASS, N_MU]
    const float* __restrict__ inp_sc,  // [KIN, N_CLASS]
    const int*   __restrict__ cls_idx, // [n_idx]
    int*         __restrict__ ws_idx,  // [N_CLASS, N_MU]
    float*       __restrict__ ws_sc,   // [N_CLASS, N_MU]
    int*         __restrict__ flags)   // [N_CLASS]
{
    __shared__ unsigned long long keys[SORTN];
    const int e = blockIdx.x;
    const int c = cls_idx[e];
    const int t = threadIdx.x;

    for (int i = t; i < SORTN; i += 1024) {
        unsigned long long key;
        if (i < NCAND) {
            float f = (i < N_MU) ? q_sc[(size_t)c * N_MU + i]
                                 : inp_sc[(size_t)(i - N_MU) * N_CLASS + c];
            unsigned u = __float_as_uint(f);
            unsigned s = (u & 0x80000000u) ? ~u : (u | 0x80000000u);
            unsigned inv = ~s; // descending
            key = ((unsigned long long)inv << 32) | (unsigned)i;
        } else {
            key = 0xFFFFFFFFFFFFFFFFull; // pad sorts last
        }
        keys[i] = key;
    }
    __syncthreads();

    for (int k = 2; k <= SORTN; k <<= 1) {
        for (int j = k >> 1; j > 0; j >>= 1) {
            const int i = ((t & ~(j - 1)) << 1) | (t & (j - 1));
            const int p = i | j;
            const bool asc = ((i & k) == 0);
            unsigned long long a = keys[i], b = keys[p];
            const bool sw = asc ? (a > b) : (a < b);
            if (sw) { keys[i] = b; keys[p] = a; }
            __syncthreads();
        }
    }

    {
        unsigned long long key = keys[t];
        int idx = (int)(key & 0xFFFFFFFFu);
        unsigned s = ~((unsigned)(key >> 32));
        unsigned u = (s & 0x80000000u) ? (s & 0x7FFFFFFFu) : ~s;
        ws_idx[((size_t)c << 10) + t] = idx;
        ws_sc [((size_t)c << 10) + t] = __uint_as_float(u);
    }
    if (t == 0) flags[c] = 1;
}

// ---------------------------------------------------------------------------
// Kernel 2 (fused gather+fill): one block per (class, 8-row group).
// Staging is conflict-free: main loop index m = t + 256j over 8x512 mu
// elements -> r = m>>9 (wave-uniform), k = m&511 (lane-contiguous) ->
//   - global reads: scalar dwords, 256 B/wave fully coalesced
//   - LDS writes: stride-1 floats (2-way aliasing = free)
// Source row pointers resolved once into an 8-entry LDS table (gather via
// ws_idx when flags[c]=1, passthrough otherwise). Store phase: contiguous
// b128 LDS reads + aligned f4 nontemporal stores (16416 B region / block).
// ---------------------------------------------------------------------------
__global__ __launch_bounds__(256) void out_kernel(
    const float* __restrict__ q_mu,   // [N_CLASS, N_MU, DIM]
    const float* __restrict__ q_sc,   // [N_CLASS, N_MU]
    const float* __restrict__ inp_mu, // [KIN, DIM]
    const int*   __restrict__ ws_idx, // [N_CLASS, N_MU]
    const float* __restrict__ ws_sc,  // [N_CLASS, N_MU]
    const int*   __restrict__ flags,  // [N_CLASS]
    float*       __restrict__ out)    // [N_CLASS, N_MU, DIM+1]
{
    __shared__ __align__(16) float buf[RPB * (DIM + 1)]; // 4104 floats
    __shared__ const float* selp[RPB];                   // per-row source ptr
    __shared__ float        ssc[RPB];                    // per-row score

    const int b  = blockIdx.x;
    const int c  = b >> 7;          // 128 groups per class
    const int g  = b & 127;
    const int j0 = g * RPB;
    const int t  = threadIdx.x;
    const size_t rowbase = ((size_t)c << 10) + j0;

    if (t < RPB) {
        const bool upd = (flags[c] != 0);
        if (upd) {
            const int idx = ws_idx[rowbase + t];
            selp[t] = (idx < N_MU) ? q_mu + (((size_t)c << 10) + idx) * DIM
                                   : inp_mu + (size_t)(idx - N_MU) * DIM;
            ssc[t] = ws_sc[rowbase + t];
        } else {
            selp[t] = q_mu + (rowbase + t) * DIM;
            ssc[t] = q_sc[rowbase + t];
        }
    }
    __syncthreads();

    // stage 8 x 512 mu elements: 16 fully-coalesced scalar iterations
#pragma unroll
    for (int j = 0; j < 16; ++j) {
        const int m = t + 256 * j;    // 0..4095
        const int r = m >> 9;         // row 0..7 (wave-uniform)
        const int k = m & 511;        // element (lane-contiguous)
        buf[513 * r + k] = selp[r][k];
    }
    if (t < RPB) buf[513 * t + DIM] = ssc[t];
    __syncthreads();

    // stream the 16416-B region out as 1026 f4 nontemporal stores
    f4* dst = (f4*)(out + rowbase * (DIM + 1));
    for (int l = t; l < RPB * (DIM + 1) / 4; l += 256) {
        __builtin_nontemporal_store(*(const f4*)(buf + l * 4), dst + l);
    }
}

extern "C" void kernel_launch(void* const* d_in, const int* in_sizes, int n_in,
                              void* d_out, int out_size, void* d_ws, size_t ws_size,
                              hipStream_t stream) {
    const float* q_mu    = (const float*)d_in[0];
    const float* q_sc    = (const float*)d_in[1];
    const float* inp_mu  = (const float*)d_in[2];
    const float* inp_sc  = (const float*)d_in[3];
    const int*   cls_idx = (const int*)d_in[4];
    float* out = (float*)d_out;
    const int n_idx = in_sizes[4];

    // workspace: [N_CLASS*N_MU int] ws_idx | [N_CLASS*N_MU float] ws_sc | [N_CLASS int] flags
    int*   ws_idx = (int*)d_ws;
    float* ws_sc  = (float*)((char*)d_ws + (size_t)N_CLASS * N_MU * sizeof(int));
    int*   flags  = (int*)((char*)d_ws + (size_t)N_CLASS * N_MU * (sizeof(int) + sizeof(float)));

    (void)hipMemsetAsync(flags, 0, N_CLASS * sizeof(int), stream);
    sort_kernel<<<n_idx, 1024, 0, stream>>>(q_sc, inp_sc, cls_idx, ws_idx, ws_sc, flags);
    out_kernel<<<N_CLASS * (N_MU / RPB), 256, 0, stream>>>(
        q_mu, q_sc, inp_mu, ws_idx, ws_sc, flags, out);
}

// Round 5
// 170.722 us; speedup vs baseline: 1.2356x; 1.2356x over previous
//
#include <hip/hip_runtime.h>
#include <hip/hip_bf16.h>

// Problem constants (fixed by the reference): N_CLASS=200, N_MU=1024, D=512, K=512
constexpr int N_CLASS = 200;
constexpr int N_MU    = 1024;
constexpr int DIM     = 512;
constexpr int KIN     = 512;
constexpr int NCAND   = N_MU + KIN;      // 1536 candidates
constexpr int SORTN   = 2048;            // next pow2
constexpr int RPW     = 8;               // rows per wave (out_kernel)

// clang ext-vector (NOT HIP_vector_type) so __builtin_nontemporal_* accepts it
typedef float f4 __attribute__((ext_vector_type(4)));

// ---------------------------------------------------------------------------
// Kernel 1: per-class stable top-1024 selection via bitonic sort.
// Key = (~sortable(score) << 32) | index  -> ascending sort == descending
// score with lower-index-first tie break (matches XLA top_k stability).
// Workspace indexed by CLASS id c. Sets flags[c]=1.
// ---------------------------------------------------------------------------
__global__ __launch_bounds__(1024) void sort_kernel(
    const float* __restrict__ q_sc,    // [N_CLASS, N_MU]
    const float* __restrict__ inp_sc,  // [KIN, N_CLASS]
    const int*   __restrict__ cls_idx, // [n_idx]
    int*         __restrict__ ws_idx,  // [N_CLASS, N_MU]
    float*       __restrict__ ws_sc,   // [N_CLASS, N_MU]
    int*         __restrict__ flags)   // [N_CLASS]
{
    __shared__ unsigned long long keys[SORTN];
    const int e = blockIdx.x;
    const int c = cls_idx[e];
    const int t = threadIdx.x;

    for (int i = t; i < SORTN; i += 1024) {
        unsigned long long key;
        if (i < NCAND) {
            float f = (i < N_MU) ? q_sc[(size_t)c * N_MU + i]
                                 : inp_sc[(size_t)(i - N_MU) * N_CLASS + c];
            unsigned u = __float_as_uint(f);
            unsigned s = (u & 0x80000000u) ? ~u : (u | 0x80000000u);
            unsigned inv = ~s; // descending
            key = ((unsigned long long)inv << 32) | (unsigned)i;
        } else {
            key = 0xFFFFFFFFFFFFFFFFull; // pad sorts last
        }
        keys[i] = key;
    }
    __syncthreads();

    for (int k = 2; k <= SORTN; k <<= 1) {
        for (int j = k >> 1; j > 0; j >>= 1) {
            const int i = ((t & ~(j - 1)) << 1) | (t & (j - 1));
            const int p = i | j;
            const bool asc = ((i & k) == 0);
            unsigned long long a = keys[i], b = keys[p];
            const bool sw = asc ? (a > b) : (a < b);
            if (sw) { keys[i] = b; keys[p] = a; }
            __syncthreads();
        }
    }

    {
        unsigned long long key = keys[t];
        int idx = (int)(key & 0xFFFFFFFFu);
        unsigned s = ~((unsigned)(key >> 32));
        unsigned u = (s & 0x80000000u) ? (s & 0x7FFFFFFFu) : ~s;
        ws_idx[((size_t)c << 10) + t] = idx;
        ws_sc [((size_t)c << 10) + t] = __uint_as_float(u);
    }
    if (t == 0) flags[c] = 1;
}

// ---------------------------------------------------------------------------
// Kernel 2 (fused gather+fill, LDS-FREE): one WAVE per output row.
// Source row = 512 aligned floats (gathered via ws_idx when flags[c]=1,
// passthrough otherwise) + 1 score. Output row starts at float offset
// 513*row, misaligned by c0 = (-row) mod 4 floats. The shift is done in
// registers: two aligned f4 loads per lane, cross-lane shift via
// __shfl_down (wave-uniform c0 branch), then 127-128 aligned nontemporal
// f4 stores + <=5 scalar head/tail floats. No LDS -> no bank conflicts,
// no __syncthreads; all global traffic is dwordx4.
// ---------------------------------------------------------------------------
__global__ __launch_bounds__(256) void out_kernel(
    const float* __restrict__ q_mu,   // [N_CLASS, N_MU, DIM]
    const float* __restrict__ q_sc,   // [N_CLASS, N_MU]
    const float* __restrict__ inp_mu, // [KIN, DIM]
    const int*   __restrict__ ws_idx, // [N_CLASS, N_MU]
    const float* __restrict__ ws_sc,  // [N_CLASS, N_MU]
    const int*   __restrict__ flags,  // [N_CLASS]
    float*       __restrict__ out)    // [N_CLASS, N_MU, DIM+1]
{
    const int lane = threadIdx.x & 63;
    const size_t wave = (size_t)blockIdx.x * 4 + (threadIdx.x >> 6);
    const size_t row0 = wave * RPW;

#pragma unroll 2
    for (int rr = 0; rr < RPW; ++rr) {
        const size_t row = row0 + rr;          // 0..204799
        const int c = (int)(row >> 10);
        const float* P; float S;
        if (flags[c] != 0) {
            const int idx = ws_idx[row];
            P = (idx < N_MU) ? q_mu + ((((size_t)c << 10) + (size_t)idx) * DIM)
                             : inp_mu + (size_t)(idx - N_MU) * DIM;
            S = ws_sc[row];
        } else {
            P = q_mu + row * DIM;
            S = q_sc[row];
        }
        const size_t O = row * (size_t)(DIM + 1); // out float offset
        const int c0 = (int)((4 - (O & 3)) & 3);  // head misalign (wave-uniform)
        const int n_full = (513 - c0) >> 2;       // 127 or 128 aligned slots

        const f4* Pv = (const f4*)P;
        const f4 v0 = Pv[lane];        // floats 4l .. 4l+3
        const f4 v1 = Pv[64 + lane];   // floats 256+4l .. +3

        f4 o0, o1;
        if (c0 == 0) {
            o0 = v0; o1 = v1;          // no shift needed (25% of rows)
        } else {
            f4 nb0, nb1;               // neighbor f4 (next 16B window)
#pragma unroll
            for (int i = 0; i < 4; ++i) {
                const float d0 = __shfl_down(v0[i], 1);
                const float b1 = __shfl(v1[i], 0);     // lane0's v1 for lane63
                nb0[i] = (lane == 63) ? b1 : d0;
                const float d1 = __shfl_down(v1[i], 1);
                nb1[i] = (lane == 63) ? S : d1;        // q>=512 -> score
            }
            if (c0 == 1) {
                o0 = f4{v0.y, v0.z, v0.w, nb0.x};
                o1 = f4{v1.y, v1.z, v1.w, nb1.x};
            } else if (c0 == 2) {
                o0 = f4{v0.z, v0.w, nb0.x, nb0.y};
                o1 = f4{v1.z, v1.w, nb1.x, nb1.y};
            } else {
                o0 = f4{v0.w, nb0.x, nb0.y, nb0.z};
                o1 = f4{v1.w, nb1.x, nb1.y, nb1.z};
            }
        }
        f4* outv = (f4*)(out + O + c0);            // 16B-aligned
        __builtin_nontemporal_store(o0, outv + lane);
        if (lane < n_full - 64)
            __builtin_nontemporal_store(o1, outv + 64 + lane);

        // head floats [0, c0) and tail floats [c0+4*n_full, 513)
        if (lane < c0) out[O + lane] = P[lane];
        const int tail  = c0 + 4 * n_full;
        const int ntail = 513 - tail;              // 0..3
        if (lane >= 8 && lane < 8 + ntail) {
            const int q = tail + (lane - 8);
            out[O + q] = (q < 512) ? P[q] : S;
        }
    }
}

extern "C" void kernel_launch(void* const* d_in, const int* in_sizes, int n_in,
                              void* d_out, int out_size, void* d_ws, size_t ws_size,
                              hipStream_t stream) {
    const float* q_mu    = (const float*)d_in[0];
    const float* q_sc    = (const float*)d_in[1];
    const float* inp_mu  = (const float*)d_in[2];
    const float* inp_sc  = (const float*)d_in[3];
    const int*   cls_idx = (const int*)d_in[4];
    float* out = (float*)d_out;
    const int n_idx = in_sizes[4];

    // workspace: [N_CLASS*N_MU int] ws_idx | [N_CLASS*N_MU float] ws_sc | [N_CLASS int] flags
    int*   ws_idx = (int*)d_ws;
    float* ws_sc  = (float*)((char*)d_ws + (size_t)N_CLASS * N_MU * sizeof(int));
    int*   flags  = (int*)((char*)d_ws + (size_t)N_CLASS * N_MU * (sizeof(int) + sizeof(float)));

    (void)hipMemsetAsync(flags, 0, N_CLASS * sizeof(int), stream);
    sort_kernel<<<n_idx, 1024, 0, stream>>>(q_sc, inp_sc, cls_idx, ws_idx, ws_sc, flags);
    // one wave per row, 4 waves/block, RPW rows per wave
    const int total_rows = N_CLASS * N_MU;                 // 204800
    const int blocks = total_rows / (4 * RPW);             // 6400
    out_kernel<<<blocks, 256, 0, stream>>>(
        q_mu, q_sc, inp_mu, ws_idx, ws_sc, flags, out);
}